// Round 3
// baseline (111.706 us; speedup 1.0000x reference)
//
#include <hip/hip_runtime.h>

// mask[b, i, j] = (i < len_q[b]) & (j < len_k[b]);  out is int32 (0 / 1)
// B=32, SEQ=2048  ->  out_size = 32*2048*2048 = 134,217,728 ints (512 MiB)
//
// Pure streaming-write kernel. 8192 blocks x 256 threads; each block owns
// 8 contiguous rows (4096 int4 = 32 KB); 16 nontemporal int4 stores/thread.

constexpr int SEQ = 2048;
constexpr int ROWS_PER_BLOCK = 8;                 // divides SEQ -> no batch straddle
constexpr int INT4_PER_ROW = SEQ / 4;             // 512

typedef int int4v __attribute__((ext_vector_type(4)));

__global__ __launch_bounds__(256) void padmask_kernel(
        const int* __restrict__ len_q,
        const int* __restrict__ len_k,
        int* __restrict__ out) {
    const int block   = blockIdx.x;
    const int rowbase = block * ROWS_PER_BLOCK;   // first row of this block
    const int b       = rowbase >> 11;            // / SEQ
    const int i0      = rowbase & (SEQ - 1);

    const int lq = len_q[b];
    const int lk = len_k[b];

    int4v* out4 = reinterpret_cast<int4v*>(out) +
                  (size_t)block * (ROWS_PER_BLOCK * INT4_PER_ROW);
    const int t = threadIdx.x;

    #pragma unroll
    for (int k = 0; k < 2 * ROWS_PER_BLOCK; ++k) {
        const int i  = i0 + (k >> 1);             // wave-uniform row
        const bool qv = (i < lq);
        const int j  = (t + (k & 1) * 256) * 4;   // column of element .x
        int4v v;
        v.x = (qv && (j + 0) < lk) ? 1 : 0;
        v.y = (qv && (j + 1) < lk) ? 1 : 0;
        v.z = (qv && (j + 2) < lk) ? 1 : 0;
        v.w = (qv && (j + 3) < lk) ? 1 : 0;
        __builtin_nontemporal_store(v, &out4[t + k * 256]);
    }
}

extern "C" void kernel_launch(void* const* d_in, const int* in_sizes, int n_in,
                              void* d_out, int out_size, void* d_ws, size_t ws_size,
                              hipStream_t stream) {
    const int* len_q = (const int*)d_in[0];
    const int* len_k = (const int*)d_in[1];
    int* out = (int*)d_out;

    const int batch  = in_sizes[0];                          // 32
    const int n_rows = batch * SEQ;                          // 65536
    const int blocks = n_rows / ROWS_PER_BLOCK;              // 8192

    padmask_kernel<<<blocks, 256, 0, stream>>>(len_q, len_k, out);
}

// Round 4
// 104.806 us; speedup vs baseline: 1.0658x; 1.0658x over previous
//
#include <hip/hip_runtime.h>

// mask[b, i, j] = (i < len_q[b]) & (j < len_k[b]);  out is int32 (0 / 1)
// B=32, SEQ=2048  ->  out_size = 32*2048*2048 = 134,217,728 ints (512 MiB)
//
// Pure streaming-write kernel. 8192 blocks x 256 threads; each block owns
// 8 contiguous rows (4096 int4 = 32 KB); 16 PLAIN int4 stores/thread.
// (Round-3 A/B: nontemporal stores regressed 93->112 us; reverted to plain.)

constexpr int SEQ = 2048;
constexpr int ROWS_PER_BLOCK = 8;                 // divides SEQ -> no batch straddle
constexpr int INT4_PER_ROW = SEQ / 4;             // 512

typedef int int4v __attribute__((ext_vector_type(4)));

__global__ __launch_bounds__(256) void padmask_kernel(
        const int* __restrict__ len_q,
        const int* __restrict__ len_k,
        int* __restrict__ out) {
    const int block   = blockIdx.x;
    const int rowbase = block * ROWS_PER_BLOCK;   // first row of this block
    const int b       = rowbase >> 11;            // / SEQ
    const int i0      = rowbase & (SEQ - 1);

    const int lq = len_q[b];
    const int lk = len_k[b];

    int4v* out4 = reinterpret_cast<int4v*>(out) +
                  (size_t)block * (ROWS_PER_BLOCK * INT4_PER_ROW);
    const int t = threadIdx.x;

    #pragma unroll
    for (int k = 0; k < 2 * ROWS_PER_BLOCK; ++k) {
        const int i  = i0 + (k >> 1);             // wave-uniform row
        const bool qv = (i < lq);
        const int j  = (t + (k & 1) * 256) * 4;   // column of element .x
        int4v v;
        v.x = (qv && (j + 0) < lk) ? 1 : 0;
        v.y = (qv && (j + 1) < lk) ? 1 : 0;
        v.z = (qv && (j + 2) < lk) ? 1 : 0;
        v.w = (qv && (j + 3) < lk) ? 1 : 0;
        out4[t + k * 256] = v;
    }
}

extern "C" void kernel_launch(void* const* d_in, const int* in_sizes, int n_in,
                              void* d_out, int out_size, void* d_ws, size_t ws_size,
                              hipStream_t stream) {
    const int* len_q = (const int*)d_in[0];
    const int* len_k = (const int*)d_in[1];
    int* out = (int*)d_out;

    const int batch  = in_sizes[0];                          // 32
    const int n_rows = batch * SEQ;                          // 65536
    const int blocks = n_rows / ROWS_PER_BLOCK;              // 8192

    padmask_kernel<<<blocks, 256, 0, stream>>>(len_q, len_k, out);
}